// Round 1
// baseline (360.683 us; speedup 1.0000x reference)
//
#include <hip/hip_runtime.h>
#include <hip/hip_bf16.h>
#include <stdint.h>

typedef __attribute__((ext_vector_type(8))) short short8;
typedef __attribute__((ext_vector_type(8))) unsigned short ushort8;
typedef __attribute__((ext_vector_type(4))) float f32x4;

// ---------------- conversion kernels (memory-bound) ----------------

__device__ inline unsigned short f2bf_rne(float f) {
    union { float f; unsigned int u; } v; v.f = f;
    unsigned int u = v.u;
    unsigned int r = u + 0x7FFFu + ((u >> 16) & 1u);
    return (unsigned short)(r >> 16);
}

// x fp32 -> bf16 (RNE), 8 elems/thread
__global__ __launch_bounds__(256) void cvt_x_kernel(const float* __restrict__ in,
                                                    unsigned short* __restrict__ out,
                                                    int n8) {
    int i = blockIdx.x * blockDim.x + threadIdx.x;
    if (i >= n8) return;
    const float4* p = reinterpret_cast<const float4*>(in) + (size_t)i * 2;
    float4 a = p[0];
    float4 b = p[1];
    ushort8 o;
    o[0] = f2bf_rne(a.x); o[1] = f2bf_rne(a.y); o[2] = f2bf_rne(a.z); o[3] = f2bf_rne(a.w);
    o[4] = f2bf_rne(b.x); o[5] = f2bf_rne(b.y); o[6] = f2bf_rne(b.z); o[7] = f2bf_rne(b.w);
    *reinterpret_cast<ushort8*>(out + (size_t)i * 8) = o;
}

__device__ inline unsigned short signbf(float f) {
    return (f > 0.0f) ? (unsigned short)0x3F80u
         : (f < 0.0f) ? (unsigned short)0xBF80u
                      : (unsigned short)0u;
}

// W fp32 -> sign(W) as bf16 {-1,0,+1}, 8 elems/thread
__global__ __launch_bounds__(256) void cvt_w_kernel(const float* __restrict__ in,
                                                    unsigned short* __restrict__ out,
                                                    int n8) {
    int i = blockIdx.x * blockDim.x + threadIdx.x;
    if (i >= n8) return;
    const float4* p = reinterpret_cast<const float4*>(in) + (size_t)i * 2;
    float4 a = p[0];
    float4 b = p[1];
    ushort8 o;
    o[0] = signbf(a.x); o[1] = signbf(a.y); o[2] = signbf(a.z); o[3] = signbf(a.w);
    o[4] = signbf(b.x); o[5] = signbf(b.y); o[6] = signbf(b.z); o[7] = signbf(b.w);
    *reinterpret_cast<ushort8*>(out + (size_t)i * 8) = o;
}

// ---------------- bf16 MFMA GEMM: C = A @ B^T + bias ----------------
// A: [M][K] bf16 row-major (x). B: [N][K] bf16 row-major (sign(W), row=out).
// C: [M][N] fp32. m97 structure: 128x128 tile, BK=32, 4 waves (2x2), each
// wave computes 64x64 via 4x4 frags of 16x16x32 MFMA; global_load_lds w=16.

#define BM 128
#define BN 128
#define BK 32

__device__ inline void gload_lds16(const void* g, void* l) {
    __builtin_amdgcn_global_load_lds(
        (const __attribute__((address_space(1))) unsigned int*)g,
        (__attribute__((address_space(3))) unsigned int*)l,
        16, 0, 0);
}

__global__ __launch_bounds__(256) void gemm_bt_bias(
    const unsigned short* __restrict__ A,
    const unsigned short* __restrict__ B,
    const float* __restrict__ bias,
    float* __restrict__ C,
    int M, int N, int K)
{
    __shared__ unsigned short sA[BM * BK];  // [128][32] bf16, 8 KB
    __shared__ unsigned short sB[BN * BK];

    const int tid  = threadIdx.x;
    const int wid  = tid >> 6;
    const int lane = tid & 63;
    const int brow = blockIdx.y * BM;
    const int bcol = blockIdx.x * BN;
    const int wr = wid >> 1;      // 2x2 wave grid
    const int wc = wid & 1;

    // staging coords: chunk c = wid*2+j covers rows c*16..c*16+15, this lane:
    const int st_r  = (lane >> 2);        // +c*16
    const int st_c  = (lane & 3) * 8;     // bf16 col in [0,32)

    f32x4 acc[4][4];
#pragma unroll
    for (int m = 0; m < 4; ++m)
#pragma unroll
        for (int n = 0; n < 4; ++n)
            acc[m][n] = (f32x4){0.f, 0.f, 0.f, 0.f};

    for (int k0 = 0; k0 < K; k0 += BK) {
        __syncthreads();  // all waves done reading LDS from previous step
#pragma unroll
        for (int j = 0; j < 2; ++j) {
            const int c = wid * 2 + j;            // chunk 0..7
            const int r = c * 16 + st_r;
            const unsigned short* ga = A + (size_t)(brow + r) * K + k0 + st_c;
            gload_lds16(ga, sA + c * 512);        // wave-uniform LDS base
            const unsigned short* gb = B + (size_t)(bcol + r) * K + k0 + st_c;
            gload_lds16(gb, sB + c * 512);
        }
        __syncthreads();  // implicit vmcnt(0) drains global_load_lds

        short8 af[4], bf[4];
        const int kc = (lane >> 4) * 8;           // k sub-offset per lane group
#pragma unroll
        for (int m = 0; m < 4; ++m) {
            const int row = wr * 64 + m * 16 + (lane & 15);
            af[m] = *reinterpret_cast<const short8*>(&sA[row * BK + kc]);
        }
#pragma unroll
        for (int n = 0; n < 4; ++n) {
            const int row = wc * 64 + n * 16 + (lane & 15);
            bf[n] = *reinterpret_cast<const short8*>(&sB[row * BK + kc]);
        }
#pragma unroll
        for (int m = 0; m < 4; ++m)
#pragma unroll
            for (int n = 0; n < 4; ++n)
                acc[m][n] = __builtin_amdgcn_mfma_f32_16x16x32_bf16(
                    af[m], bf[n], acc[m][n], 0, 0, 0);
    }

    // epilogue: C[row][col] = acc + bias[col]
    // C/D layout (verified m89/m91): col = lane&15, row = (lane>>4)*4 + j
#pragma unroll
    for (int n = 0; n < 4; ++n) {
        const int col = bcol + wc * 64 + n * 16 + (lane & 15);
        const float bv = bias[col];
#pragma unroll
        for (int m = 0; m < 4; ++m) {
            const int row0 = brow + wr * 64 + m * 16 + (lane >> 4) * 4;
#pragma unroll
            for (int j = 0; j < 4; ++j) {
                C[(size_t)(row0 + j) * N + col] = acc[m][n][j] + bv;
            }
        }
    }
}

// ---------------- launcher ----------------

extern "C" void kernel_launch(void* const* d_in, const int* in_sizes, int n_in,
                              void* d_out, int out_size, void* d_ws, size_t ws_size,
                              hipStream_t stream) {
    const float* x  = (const float*)d_in[0];
    const float* W  = (const float*)d_in[1];
    const float* bv = (const float*)d_in[2];
    float* out = (float*)d_out;

    const int OUT = in_sizes[2];                 // 4096
    const int IN  = in_sizes[1] / OUT;           // 4096
    const int M   = in_sizes[0] / IN;            // 4096

    unsigned short* xb = (unsigned short*)d_ws;              // [M][IN] bf16
    unsigned short* wb = xb + (size_t)M * IN;                // [OUT][IN] bf16

    {
        const int n8 = (M * IN) / 8;
        cvt_x_kernel<<<(n8 + 255) / 256, 256, 0, stream>>>(x, xb, n8);
    }
    {
        const int n8 = (OUT * IN) / 8;
        cvt_w_kernel<<<(n8 + 255) / 256, 256, 0, stream>>>(W, wb, n8);
    }
    gemm_bt_bias<<<dim3(OUT / BN, M / BM), 256, 0, stream>>>(
        xb, wb, bv, out, M, OUT, IN);
}

// Round 2
// 290.440 us; speedup vs baseline: 1.2419x; 1.2419x over previous
//
#include <hip/hip_runtime.h>
#include <hip/hip_bf16.h>
#include <stdint.h>

typedef __attribute__((ext_vector_type(8))) short short8;
typedef __attribute__((ext_vector_type(8))) unsigned short ushort8;
typedef __attribute__((ext_vector_type(4))) float f32x4;
typedef unsigned short ushort_t;

// ---------------- conversion kernels (memory-bound) ----------------

__device__ inline unsigned short f2bf_rne(float f) {
    union { float f; unsigned int u; } v; v.f = f;
    unsigned int u = v.u;
    unsigned int r = u + 0x7FFFu + ((u >> 16) & 1u);
    return (unsigned short)(r >> 16);
}

__global__ __launch_bounds__(256) void cvt_x_kernel(const float* __restrict__ in,
                                                    unsigned short* __restrict__ out,
                                                    int n8) {
    int i = blockIdx.x * blockDim.x + threadIdx.x;
    if (i >= n8) return;
    const float4* p = reinterpret_cast<const float4*>(in) + (size_t)i * 2;
    float4 a = p[0];
    float4 b = p[1];
    ushort8 o;
    o[0] = f2bf_rne(a.x); o[1] = f2bf_rne(a.y); o[2] = f2bf_rne(a.z); o[3] = f2bf_rne(a.w);
    o[4] = f2bf_rne(b.x); o[5] = f2bf_rne(b.y); o[6] = f2bf_rne(b.z); o[7] = f2bf_rne(b.w);
    *reinterpret_cast<ushort8*>(out + (size_t)i * 8) = o;
}

__device__ inline unsigned short signbf(float f) {
    return (f > 0.0f) ? (unsigned short)0x3F80u
         : (f < 0.0f) ? (unsigned short)0xBF80u
                      : (unsigned short)0u;
}

__global__ __launch_bounds__(256) void cvt_w_kernel(const float* __restrict__ in,
                                                    unsigned short* __restrict__ out,
                                                    int n8) {
    int i = blockIdx.x * blockDim.x + threadIdx.x;
    if (i >= n8) return;
    const float4* p = reinterpret_cast<const float4*>(in) + (size_t)i * 2;
    float4 a = p[0];
    float4 b = p[1];
    ushort8 o;
    o[0] = signbf(a.x); o[1] = signbf(a.y); o[2] = signbf(a.z); o[3] = signbf(a.w);
    o[4] = signbf(b.x); o[5] = signbf(b.y); o[6] = signbf(b.z); o[7] = signbf(b.w);
    *reinterpret_cast<ushort8*>(out + (size_t)i * 8) = o;
}

// ---------------- 256x256 8-wave phase-split bf16 GEMM: C = A @ B^T + bias ---
// A: [M][K] bf16 (x).  B: [N][K] bf16 (sign(W)).  C: [M][N] fp32.
// 512 threads = 8 waves (2 M x 4 N), per-wave output 128x64 (8x4 frags of
// 16x16x32). BK=64, double-buffered LDS 128 KiB, T2 XOR swizzle, T5 setprio.
// Staging: tile t+1 issued at start of tile t, drained by end-of-tile sync.

#define BM 256
#define BN 256
#define BK 64

__device__ __forceinline__ void gload_lds16(const void* g, void* l) {
    __builtin_amdgcn_global_load_lds(
        (const __attribute__((address_space(1))) unsigned int*)g,
        (__attribute__((address_space(3))) unsigned int*)l,
        16, 0, 0);
}

__device__ __forceinline__ void phase_barrier() {
    __builtin_amdgcn_sched_barrier(0);
    __builtin_amdgcn_s_barrier();
    __builtin_amdgcn_sched_barrier(0);
}

// stage one 256x64 K-tile of A and B into the given LDS buffer bases.
// swizzle (T2, rule #21): LDS dest linear; global source col16 pre-permuted:
// lane l covers row (h*128 + r*64 + wid*8 + (l>>3)), col16 = (l&7) ^ (l>>3).
__device__ __forceinline__ void stage_tile(
    const ushort_t* __restrict__ A, const ushort_t* __restrict__ B,
    ushort_t* ldsA, ushort_t* ldsB,
    int brow, int bcol, int kbase, int K,
    int wid, int srow, int scol)
{
#pragma unroll
    for (int h = 0; h < 2; ++h)
#pragma unroll
        for (int r = 0; r < 2; ++r) {
            const int rowoff = h * 128 + r * 64 + wid * 8;   // wave-uniform
            const ushort_t* ga = A + (size_t)(brow + rowoff + srow) * K + kbase + scol;
            gload_lds16(ga, ldsA + rowoff * 64);
            const ushort_t* gb = B + (size_t)(bcol + rowoff + srow) * K + kbase + scol;
            gload_lds16(gb, ldsB + rowoff * 64);
        }
}

__global__ __launch_bounds__(512, 2) void gemm8_bt_bias(
    const ushort_t* __restrict__ A,
    const ushort_t* __restrict__ B,
    const float* __restrict__ bias,
    float* __restrict__ C,
    int M, int N, int K, int tn_n)
{
    extern __shared__ ushort_t lds[];
    // ushort layout: A buf: [buf*16384 + half*8192 + row*64 + col]
    //                B buf: 32768 + same

    const int tid  = threadIdx.x;
    const int wid  = tid >> 6;
    const int lane = tid & 63;
    const int wr = wid >> 2;       // 0..1 (M)
    const int wc = wid & 3;        // 0..3 (N)

    // XCD-aware bijective swizzle (m204)
    unsigned nwg = gridDim.x, orig = blockIdx.x;
    unsigned qd = nwg >> 3, rm = nwg & 7u;
    unsigned xcd = orig & 7u, sub = orig >> 3;
    unsigned id = (xcd < rm ? xcd * (qd + 1) : rm * (qd + 1) + (xcd - rm) * qd) + sub;
    const int tm = (int)(id / (unsigned)tn_n);
    const int tn = (int)(id % (unsigned)tn_n);
    const int brow = tm * BM;
    const int bcol = tn * BN;

    const int nt = K / BK;

    // staging per-lane constants
    const int srow = lane >> 3;                       // 0..7
    const int scol = ((lane & 7) ^ srow) << 3;        // element offset (inv-swz)

    // frag-read per-lane constants
    const int r15 = lane & 15;
    const int hi2 = lane >> 4;                        // 0..3
    const int l7  = lane & 7;
    const int sK0 = ((hi2) ^ l7) * 8;                 // kk=0 swizzled slot (ushorts)
    const int sK1 = ((4 + hi2) ^ l7) * 8;             // kk=1
    const int bRow = (wc & 1) * 64;                   // B local row base in its half

    f32x4 acc[8][4];
#pragma unroll
    for (int m = 0; m < 8; ++m)
#pragma unroll
        for (int n = 0; n < 4; ++n)
            acc[m][n] = (f32x4){0.f, 0.f, 0.f, 0.f};

    // prologue: stage tile 0 into buf 0
    stage_tile(A, B, lds, lds + 32768, brow, bcol, 0, K, wid, srow, scol);
    __syncthreads();

    short8 aF[2][4], bF[2][4];

#pragma unroll 2
    for (int t = 0; t < nt; ++t) {
        const int cur = t & 1;
        const ushort_t* aC = lds + cur * 16384 + wr * 8192;
        const ushort_t* bC = lds + 32768 + cur * 16384 + (wc >> 1) * 8192;

        // issue next tile's staging first (in flight across all 4 phases)
        if (t + 1 < nt) {
            const int nxt = cur ^ 1;
            stage_tile(A, B, lds + nxt * 16384, lds + 32768 + nxt * 16384,
                       brow, bcol, (t + 1) * BK, K, wid, srow, scol);
        }

        // ---- phase 0: read A m0-3 + B n0-1; MFMA q0 ----
#pragma unroll
        for (int i = 0; i < 4; ++i) {
            aF[0][i] = *reinterpret_cast<const short8*>(aC + (i * 16 + r15) * 64 + sK0);
            aF[1][i] = *reinterpret_cast<const short8*>(aC + (i * 16 + r15) * 64 + sK1);
        }
#pragma unroll
        for (int n = 0; n < 2; ++n) {
            bF[0][n] = *reinterpret_cast<const short8*>(bC + (bRow + n * 16 + r15) * 64 + sK0);
            bF[1][n] = *reinterpret_cast<const short8*>(bC + (bRow + n * 16 + r15) * 64 + sK1);
        }
        phase_barrier();
        __builtin_amdgcn_s_setprio(1);
#pragma unroll
        for (int i = 0; i < 4; ++i)
#pragma unroll
            for (int j = 0; j < 2; ++j) {
                f32x4 c = acc[i][j];
                c = __builtin_amdgcn_mfma_f32_16x16x32_bf16(aF[0][i], bF[0][j], c, 0, 0, 0);
                c = __builtin_amdgcn_mfma_f32_16x16x32_bf16(aF[1][i], bF[1][j], c, 0, 0, 0);
                acc[i][j] = c;
            }
        __builtin_amdgcn_s_setprio(0);
        phase_barrier();

        // ---- phase 1: read B n2-3; MFMA q1 ----
#pragma unroll
        for (int n = 2; n < 4; ++n) {
            bF[0][n] = *reinterpret_cast<const short8*>(bC + (bRow + n * 16 + r15) * 64 + sK0);
            bF[1][n] = *reinterpret_cast<const short8*>(bC + (bRow + n * 16 + r15) * 64 + sK1);
        }
        phase_barrier();
        __builtin_amdgcn_s_setprio(1);
#pragma unroll
        for (int i = 0; i < 4; ++i)
#pragma unroll
            for (int j = 2; j < 4; ++j) {
                f32x4 c = acc[i][j];
                c = __builtin_amdgcn_mfma_f32_16x16x32_bf16(aF[0][i], bF[0][j], c, 0, 0, 0);
                c = __builtin_amdgcn_mfma_f32_16x16x32_bf16(aF[1][i], bF[1][j], c, 0, 0, 0);
                acc[i][j] = c;
            }
        __builtin_amdgcn_s_setprio(0);
        phase_barrier();

        // ---- phase 2: read A m4-7; MFMA q2 ----
#pragma unroll
        for (int i = 0; i < 4; ++i) {
            aF[0][i] = *reinterpret_cast<const short8*>(aC + ((4 + i) * 16 + r15) * 64 + sK0);
            aF[1][i] = *reinterpret_cast<const short8*>(aC + ((4 + i) * 16 + r15) * 64 + sK1);
        }
        phase_barrier();
        __builtin_amdgcn_s_setprio(1);
#pragma unroll
        for (int i = 0; i < 4; ++i)
#pragma unroll
            for (int j = 0; j < 2; ++j) {
                f32x4 c = acc[4 + i][j];
                c = __builtin_amdgcn_mfma_f32_16x16x32_bf16(aF[0][i], bF[0][j], c, 0, 0, 0);
                c = __builtin_amdgcn_mfma_f32_16x16x32_bf16(aF[1][i], bF[1][j], c, 0, 0, 0);
                acc[4 + i][j] = c;
            }
        __builtin_amdgcn_s_setprio(0);
        phase_barrier();

        // ---- phase 3: MFMA q3 (no new reads) ----
        __builtin_amdgcn_s_setprio(1);
#pragma unroll
        for (int i = 0; i < 4; ++i)
#pragma unroll
            for (int j = 2; j < 4; ++j) {
                f32x4 c = acc[4 + i][j];
                c = __builtin_amdgcn_mfma_f32_16x16x32_bf16(aF[0][i], bF[0][j], c, 0, 0, 0);
                c = __builtin_amdgcn_mfma_f32_16x16x32_bf16(aF[1][i], bF[1][j], c, 0, 0, 0);
                acc[4 + i][j] = c;
            }
        __builtin_amdgcn_s_setprio(0);

        // tile boundary: drains vmcnt(0) (tile t+1 landed) + block sync
        __syncthreads();
    }

    // epilogue: C[row][col] = acc + bias[col]
    // C/D layout (m89/m91): col = lane&15, row = (lane>>4)*4 + j
#pragma unroll
    for (int n = 0; n < 4; ++n) {
        const int col = bcol + wc * 64 + n * 16 + r15;
        const float bv = bias[col];
#pragma unroll
        for (int m = 0; m < 8; ++m) {
            const int row0 = brow + wr * 128 + m * 16 + hi2 * 4;
#pragma unroll
            for (int j = 0; j < 4; ++j) {
                C[(size_t)(row0 + j) * N + col] = acc[m][n][j] + bv;
            }
        }
    }
}

// ---------------- launcher ----------------

extern "C" void kernel_launch(void* const* d_in, const int* in_sizes, int n_in,
                              void* d_out, int out_size, void* d_ws, size_t ws_size,
                              hipStream_t stream) {
    const float* x  = (const float*)d_in[0];
    const float* W  = (const float*)d_in[1];
    const float* bv = (const float*)d_in[2];
    float* out = (float*)d_out;

    const int OUT = in_sizes[2];                 // 4096
    const int IN  = in_sizes[1] / OUT;           // 4096
    const int M   = in_sizes[0] / IN;            // 4096

    unsigned short* xb = (unsigned short*)d_ws;              // [M][IN] bf16
    unsigned short* wb = xb + (size_t)M * IN;                // [OUT][IN] bf16

    {
        const int n8 = (M * IN) / 8;
        cvt_x_kernel<<<(n8 + 255) / 256, 256, 0, stream>>>(x, xb, n8);
    }
    {
        const int n8 = (OUT * IN) / 8;
        cvt_w_kernel<<<(n8 + 255) / 256, 256, 0, stream>>>(W, wb, n8);
    }

    const int tn_n = OUT / BN;
    const int tm_n = M / BM;
    const int nblk = tn_n * tm_n;
    // 128 KiB dynamic LDS: raise the cap (idempotent; not a stream op)
    (void)hipFuncSetAttribute((const void*)gemm8_bt_bias,
                              hipFuncAttributeMaxDynamicSharedMemorySize, 131072);
    gemm8_bt_bias<<<nblk, 512, 131072, stream>>>(xb, wb, bv, out, M, OUT, IN, tn_n);
}